// Round 14
// baseline (340.783 us; speedup 1.0000x reference)
//
#include <hip/hip_runtime.h>

typedef unsigned short u16;
typedef unsigned long long u64;
typedef __attribute__((ext_vector_type(4))) float f32x4;
typedef __attribute__((ext_vector_type(8))) short bf16x8;
typedef __attribute__((ext_vector_type(8))) u16 u16x8;
typedef __attribute__((ext_vector_type(4))) u16 u16x4v;
typedef __attribute__((ext_vector_type(2))) u64 u64x2;

#define DI __device__ __forceinline__

DI u16 f2bf(float f) {
  unsigned int x = __float_as_uint(f);
  unsigned int r = (x + 0x7fffu + ((x >> 16) & 1u)) >> 16;
  return (u16)r;
}
DI float bf2f(u16 u) { return __uint_as_float(((unsigned int)u) << 16); }
DI u64 shfl64(u64 v, int src) {
  int lo = __shfl((int)(unsigned int)(v & 0xffffffffu), src, 64);
  int hi = __shfl((int)(unsigned int)(v >> 32), src, 64);
  return ((u64)(unsigned int)hi << 32) | (u64)(unsigned int)lo;
}

// ---------------------------------------------------------------------------
// K0: pack weights + transpose masks.
// ---------------------------------------------------------------------------
__global__ __launch_bounds__(256) void pack_kernel(
    const float* __restrict__ qw, const float* __restrict__ qb,
    const float* __restrict__ kw, const float* __restrict__ kb,
    const float* __restrict__ vw, const float* __restrict__ vb,
    const float* __restrict__ ow,
    const float* __restrict__ mw, const float* __restrict__ mh,
    u16* __restrict__ wqkvT, float* __restrict__ bias, u16* __restrict__ owT,
    float* __restrict__ maskTw, float* __restrict__ maskTh)
{
  const int r = blockIdx.x;   // 0..1279
  const int t = threadIdx.x;  // 0..255
  if (r < 768) {
    const int p = r >> 8, c = r & 255;
    const float* wsrc = p == 0 ? qw : (p == 1 ? kw : vw);
    const float sc = (p == 1) ? 0.17677669529663687f : 1.0f;  // 1/sqrt(32)
    wqkvT[r * 256 + t] = f2bf(wsrc[t * 256 + c] * sc);
    if (t == 0) {
      const float* bs = p == 0 ? qb : (p == 1 ? kb : vb);
      bias[r] = bs[c] * sc;
    }
  } else if (r < 1024) {
    const int c = r - 768;
    owT[c * 256 + t] = f2bf(ow[t * 256 + c]);
  } else {
    const int r2 = r - 1024;          // 0..255
    const int sel = r2 >> 7;          // 0: mask_w, 1: mask_h
    const int n = (r2 >> 4) & 7;
    const int k = (r2 & 15) * 4 + (t >> 6);
    const int q = t & 63;
    const float* msrc = sel ? mh : mw;
    float* mdst = sel ? maskTh : maskTw;
    mdst[(n * 64 + k) * 64 + q] = msrc[(n * 64 + q) * 64 + k];
  }
}

// ---------------------------------------------------------------------------
// K1: QKV projection + bias + RoPE (EXACT R7/R12 kernel — 91.5us measured).
// ---------------------------------------------------------------------------
__global__ __launch_bounds__(256, 2) void qkv_gemm_kernel(
    const float* __restrict__ x, const u16* __restrict__ wT, const float* __restrict__ bias,
    const float* __restrict__ sinp, const float* __restrict__ cosp,
    u16* __restrict__ qr, u16* __restrict__ kr, u16* __restrict__ v)
{
  __shared__ u16 As[32768];      // 64 KB swizzled 128x256 bf16 tile
  __shared__ float Tr[4][1024];  // 16 KB: per-wave 16x64 f32 transpose slab
  const int t = threadIdx.x;
  const int wave = t >> 6, lane = t & 63;
  const int g = lane >> 4, lr = lane & 15;
  const int wr = wave >> 1, wc = wave & 1;
  const int m0 = blockIdx.x * 128;

  {  // fused convert + stage: 32 float4 chunks per thread
    char* Abw = (char*)As;
#pragma unroll
    for (int i = 0; i < 32; ++i) {
      const int c = t + 256 * i;        // f32x4 chunk, 0..8191
      const int row = c >> 6, cf = c & 63;
      const float4 xv = *reinterpret_cast<const float4*>(x + (m0 + row) * 256 + cf * 4);
      u16x4v bv;
      bv.x = f2bf(xv.x); bv.y = f2bf(xv.y); bv.z = f2bf(xv.z); bv.w = f2bf(xv.w);
      *reinterpret_cast<u16x4v*>(Abw + row * 512 + ((cf * 8) ^ ((row & 7) << 4))) = bv;
    }
  }
  __syncthreads();

  const char* Ab = (const char*)As;
  float* Trw = Tr[wave];
  const int tau = lane >> 3;        // 0..7
  const int kap = lane & 7;         // 0..7

  for (int cg = 0; cg < 6; ++cg) {
    const int c0 = cg * 128;
    f32x4 acc[4][4];
#pragma unroll
    for (int i = 0; i < 4; ++i)
#pragma unroll
      for (int j = 0; j < 4; ++j) acc[i][j] = (f32x4){0.f, 0.f, 0.f, 0.f};

#pragma unroll
    for (int ks = 0; ks < 8; ++ks) {
      bf16x8 af[4], bfr[4];
#pragma unroll
      for (int mt = 0; mt < 4; ++mt) {
        const int rr = wr * 64 + mt * 16 + lr;
        const int cb = (ks * 64 + g * 16) ^ ((rr & 7) << 4);
        af[mt] = *reinterpret_cast<const bf16x8*>(Ab + rr * 512 + cb);
      }
#pragma unroll
      for (int nt = 0; nt < 4; ++nt)
        bfr[nt] = *reinterpret_cast<const bf16x8*>(wT + (c0 + wc * 64 + nt * 16 + lr) * 256 + ks * 32 + g * 8);
#pragma unroll
      for (int mt = 0; mt < 4; ++mt)
#pragma unroll
        for (int nt = 0; nt < 4; ++nt)
          acc[mt][nt] = __builtin_amdgcn_mfma_f32_16x16x32_bf16(af[mt], bfr[nt], acc[mt][nt], 0, 0, 0);
    }

    const int colb = c0 + wc * 64;
    const int proj = colb >> 8;  // 0=q 1=k 2=v
    u16* dst = proj == 0 ? qr : (proj == 1 ? kr : v);
    const int e0 = (colb & 255) + kap * 8;

    float bcv[4];
#pragma unroll
    for (int nt = 0; nt < 4; ++nt) bcv[nt] = bias[colb + nt * 16 + lr];

#pragma unroll
    for (int mt = 0; mt < 4; ++mt) {
#pragma unroll
      for (int nt = 0; nt < 4; ++nt)
#pragma unroll
        for (int j = 0; j < 4; ++j)
          Trw[(g * 4 + j) * 64 + ((nt * 16 + lr) ^ (8 * j) ^ (16 * (g & 1)))] =
              acc[mt][nt][j] + bcv[nt];
      asm volatile("s_waitcnt lgkmcnt(0)" ::: "memory");
#pragma unroll
      for (int r2 = 0; r2 < 2; ++r2) {
        const int row = tau + 8 * r2;                    // 0..15
        const int sig = (8 * (row & 3)) ^ (16 * ((row >> 2) & 1));
        const int rb = row * 64 + ((kap * 8) ^ sig);
        const float4 v0 = *reinterpret_cast<const float4*>(Trw + rb);
        const float4 v1 = *reinterpret_cast<const float4*>(Trw + rb + 4);
        const int tok = m0 + wr * 64 + mt * 16 + row;
        u16x8 o;
        if (proj < 2) {
          const int pos = tok & 4095;        // h*64 + w
          const int d0 = (kap * 8) & 31;
          const float* sp2 = sinp + pos * 32 + d0;
          const float* cp2 = cosp + pos * 32 + d0;
          {
            const float4 s0 = *reinterpret_cast<const float4*>(sp2);
            const float4 cA = *reinterpret_cast<const float4*>(cp2);
            o[0] = f2bf(v0.x * cA.x - v0.y * s0.x);
            o[1] = f2bf(v0.y * cA.y + v0.x * s0.y);
            o[2] = f2bf(v0.z * cA.z - v0.w * s0.z);
            o[3] = f2bf(v0.w * cA.w + v0.z * s0.w);
          }
          {
            const float4 s1 = *reinterpret_cast<const float4*>(sp2 + 4);
            const float4 cB = *reinterpret_cast<const float4*>(cp2 + 4);
            o[4] = f2bf(v1.x * cB.x - v1.y * s1.x);
            o[5] = f2bf(v1.y * cB.y + v1.x * s1.y);
            o[6] = f2bf(v1.z * cB.z - v1.w * s1.z);
            o[7] = f2bf(v1.w * cB.w + v1.z * s1.w);
          }
        } else {
          o[0] = f2bf(v0.x); o[1] = f2bf(v0.y); o[2] = f2bf(v0.z); o[3] = f2bf(v0.w);
          o[4] = f2bf(v1.x); o[5] = f2bf(v1.y); o[6] = f2bf(v1.z); o[7] = f2bf(v1.w);
        }
        *reinterpret_cast<u16x8*>(dst + tok * 256 + e0) = o;
      }
      asm volatile("s_waitcnt lgkmcnt(0)" ::: "memory");
    }
  }
}

// ---------------------------------------------------------------------------
// K2/K3: axial attention, all-register softmax (R13 math, verified), now
// restructured per-qmt so everything is statically indexed and register
// pressure stays ~130 (R13's un-unrolled hh loop sent obf to scratch ->
// VGPR 60, VALUBusy 0.6%). kf hoisted, qf loaded per qmt, vb re-read per
// qmt. launch_bounds(256,3): no spill, 3 blocks/CU (LDS 40 KB).
// ---------------------------------------------------------------------------
__global__ __launch_bounds__(256, 3) void attn_kernel(
    const u16* __restrict__ qr, const u16* __restrict__ kr, const u16* __restrict__ vsrc,
    const float* __restrict__ maskT, u16* __restrict__ dst, const int mode)
{
  __shared__ u16 Vt[256][80];  // 40 KB transposed V; reused as O slab at end
  const int t = threadIdx.x;
  const int wave = t >> 6, lane = t & 63;
  const int g = lane >> 4, lr = lane & 15;
  const int b = blockIdx.x >> 6, o = blockIdx.x & 63;
  const int base = (mode == 0) ? (b * 4096 + o * 64) * 256 : (b * 4096 + o) * 256;
  const int ts = (mode == 0) ? 256 : 16384;

#pragma unroll
  for (int i = 0; i < 8; ++i) {
    const int c = t + 256 * i;          // 16B chunk, 0..2047
    const int tok = c >> 5, ch = c & 31;
    const u16x8 val = *reinterpret_cast<const u16x8*>(vsrc + base + tok * ts + ch * 8);
    const int tc = tok ^ ((ch & 7) * 8);
#pragma unroll
    for (int j = 0; j < 8; ++j) Vt[ch * 8 + j][tc] = val[j];
  }
  __syncthreads();

  u16x4v obf[2][4][2];  // deferred O^T fragments [hh][qmt][nd] — all static idx
  const f32x4 zero = (f32x4){0.f, 0.f, 0.f, 0.f};
  const int srcA = (g & 1) * 32 + lr;   // source lane for P redistribution
  const int gg = g >> 1;

#pragma unroll
  for (int hh = 0; hh < 2; ++hh) {
    const int n = wave * 2 + hh;
    bf16x8 kf[4];
#pragma unroll
    for (int mt = 0; mt < 4; ++mt)
      kf[mt] = *reinterpret_cast<const bf16x8*>(kr + base + (mt * 16 + lr) * ts + n * 32 + g * 8);
    const float* mp = maskT + n * 4096;

#pragma unroll
    for (int qmt = 0; qmt < 4; ++qmt) {
      const bf16x8 qf =
          *reinterpret_cast<const bf16x8*>(qr + base + (qmt * 16 + lr) * ts + n * 32 + g * 8);
      f32x4 st[4];  // S^T strip: k = kmt*16+g*4+j, q = qmt*16+lr
#pragma unroll
      for (int kmt = 0; kmt < 4; ++kmt)
        st[kmt] = __builtin_amdgcn_mfma_f32_16x16x32_bf16(kf[kmt], qf, zero, 0, 0, 0);
#pragma unroll
      for (int kmt = 0; kmt < 4; ++kmt)
#pragma unroll
        for (int j = 0; j < 4; ++j)
          st[kmt][j] += mp[(kmt * 16 + g * 4 + j) * 64 + qmt * 16 + lr];

      float mx = st[0][0];
#pragma unroll
      for (int kmt = 0; kmt < 4; ++kmt)
#pragma unroll
        for (int j = 0; j < 4; ++j) mx = fmaxf(mx, st[kmt][j]);
      mx = fmaxf(mx, __shfl_xor(mx, 16));
      mx = fmaxf(mx, __shfl_xor(mx, 32));
      float sum = 0.f;
#pragma unroll
      for (int kmt = 0; kmt < 4; ++kmt)
#pragma unroll
        for (int j = 0; j < 4; ++j) {
          const float p = __expf(st[kmt][j] - mx);
          st[kmt][j] = p;
          sum += p;
        }
      sum += __shfl_xor(sum, 16);
      sum += __shfl_xor(sum, 32);
      const float rs = 1.f / sum;
      u64 p64[4];
#pragma unroll
      for (int kmt = 0; kmt < 4; ++kmt) {
        const u64 a0 = f2bf(st[kmt][0] * rs);
        const u64 a1 = f2bf(st[kmt][1] * rs);
        const u64 a2 = f2bf(st[kmt][2] * rs);
        const u64 a3 = f2bf(st[kmt][3] * rs);
        p64[kmt] = a0 | (a1 << 16) | (a2 << 32) | (a3 << 48);
      }

      f32x4 oacc[2];
      oacc[0] = zero; oacc[1] = zero;
#pragma unroll
      for (int kt = 0; kt < 2; ++kt) {
        const u64 lo0 = shfl64(p64[2 * kt + 0], srcA);
        const u64 lo1 = shfl64(p64[2 * kt + 1], srcA);
        const u64 hi0 = shfl64(p64[2 * kt + 0], srcA + 16);
        const u64 hi1 = shfl64(p64[2 * kt + 1], srcA + 16);
        u64x2 qq;
        qq.x = gg ? lo1 : lo0;
        qq.y = gg ? hi1 : hi0;
        const bf16x8 pb = *reinterpret_cast<const bf16x8*>(&qq);
#pragma unroll
        for (int nd = 0; nd < 2; ++nd) {
          const int dcol = n * 32 + nd * 16 + lr;
          const bf16x8 vb = *reinterpret_cast<const bf16x8*>(
              &Vt[dcol][(kt * 32 + g * 8) ^ (((dcol >> 3) & 7) * 8)]);
          oacc[nd] = __builtin_amdgcn_mfma_f32_16x16x32_bf16(vb, pb, oacc[nd], 0, 0, 0);
        }
      }
#pragma unroll
      for (int nd = 0; nd < 2; ++nd) {
        obf[hh][qmt][nd].x = f2bf(oacc[nd][0]);
        obf[hh][qmt][nd].y = f2bf(oacc[nd][1]);
        obf[hh][qmt][nd].z = f2bf(oacc[nd][2]);
        obf[hh][qmt][nd].w = f2bf(oacc[nd][3]);
      }
    }
  }

  __syncthreads();  // Vt dead for all waves
  u16* Ow = &Vt[0][0] + wave * 4608;  // per-wave [64 tok][72] slab
#pragma unroll
  for (int hh = 0; hh < 2; ++hh)
#pragma unroll
    for (int qmt = 0; qmt < 4; ++qmt)
#pragma unroll
      for (int nd = 0; nd < 2; ++nd) {
        const int tokl = qmt * 16 + lr;
        const int col = hh * 32 + nd * 16 + g * 4;
        *reinterpret_cast<u16x4v*>(Ow + tokl * 72 + (col ^ ((tokl & 7) * 8))) = obf[hh][qmt][nd];
      }
  asm volatile("s_waitcnt lgkmcnt(0)" ::: "memory");
#pragma unroll
  for (int r = 0; r < 8; ++r) {
    const int tokl = r * 8 + (lane >> 3);
    const int kap = lane & 7;
    const u16x8 val = *reinterpret_cast<const u16x8*>(Ow + tokl * 72 + ((kap ^ (tokl & 7)) * 8));
    *reinterpret_cast<u16x8*>(dst + base + tokl * ts + wave * 64 + kap * 8) = val;
  }
}

// ---------------------------------------------------------------------------
// K4: depthwise 5x5 conv (LePE). thread = 4 consecutive w-pixels x 8 channels.
// ---------------------------------------------------------------------------
__global__ __launch_bounds__(256) void lepe_kernel(
    const u16* __restrict__ v, const float* __restrict__ cw, const float* __restrict__ cb,
    u16* __restrict__ lepe)
{
  const int t = threadIdx.x;
  const int cg = t & 31, pg = t >> 5;
  const int c0 = cg * 8;
  const int rowi = blockIdx.x >> 1;
  const int w0 = (blockIdx.x & 1) * 32 + pg * 4;
  const int h = rowi & 63;

  float acc[4][8];
#pragma unroll
  for (int p = 0; p < 4; ++p)
#pragma unroll
    for (int j = 0; j < 8; ++j) acc[p][j] = 0.f;

#pragma unroll
  for (int dy = 0; dy < 5; ++dy) {
    const int hh = h + dy - 2;
    if ((unsigned)hh >= 64u) continue;
    const u16* vrow = v + (size_t)(rowi + dy - 2) * 64 * 256 + c0;
    float fin[8][8];
#pragma unroll
    for (int i = 0; i < 8; ++i) {
      const int ww = w0 - 2 + i;
      if ((unsigned)ww < 64u) {
        const u16x8 val = *reinterpret_cast<const u16x8*>(vrow + ww * 256);
#pragma unroll
        for (int j = 0; j < 8; ++j) fin[i][j] = bf2f(val[j]);
      } else {
#pragma unroll
        for (int j = 0; j < 8; ++j) fin[i][j] = 0.f;
      }
    }
#pragma unroll
    for (int dx = 0; dx < 5; ++dx) {
      const float* wp = cw + (dy * 5 + dx) * 256 + c0;
      const float4 wA = *reinterpret_cast<const float4*>(wp);
      const float4 wB = *reinterpret_cast<const float4*>(wp + 4);
      const float wv[8] = {wA.x, wA.y, wA.z, wA.w, wB.x, wB.y, wB.z, wB.w};
#pragma unroll
      for (int p = 0; p < 4; ++p)
#pragma unroll
        for (int j = 0; j < 8; ++j)
          acc[p][j] += fin[p + dx][j] * wv[j];
    }
  }

#pragma unroll
  for (int p = 0; p < 4; ++p) {
    u16x8 r;
#pragma unroll
    for (int j = 0; j < 8; ++j) r[j] = f2bf(acc[p][j] + cb[c0 + j]);
    *reinterpret_cast<u16x8*>(lepe + ((size_t)rowi * 64 + w0 + p) * 256 + c0) = r;
  }
}

// ---------------------------------------------------------------------------
// K5: out = (attn_out + lepe) @ out_w + out_b, swapped-operand MFMA.
// ---------------------------------------------------------------------------
__global__ __launch_bounds__(256, 2) void out_gemm_kernel(
    const u16* __restrict__ ao, const u16* __restrict__ lep, const u16* __restrict__ owT,
    const float* __restrict__ ob, float* __restrict__ out)
{
  __shared__ u16 As[16384];  // 32 KB
  const int t = threadIdx.x;
  const int wave = t >> 6, lane = t & 63;
  const int g = lane >> 4, lr = lane & 15;
  const int m0 = blockIdx.x * 64;

  char* Abw = (char*)As;
#pragma unroll
  for (int i = 0; i < 8; ++i) {
    const int c = t + 256 * i;
    const int row = c >> 5, bc = (c & 31) << 4;
    const int off = (m0 + row) * 256 + (c & 31) * 8;
    const u16x8 a = *reinterpret_cast<const u16x8*>(ao + off);
    const u16x8 l = *reinterpret_cast<const u16x8*>(lep + off);
    u16x8 s;
#pragma unroll
    for (int j = 0; j < 8; ++j) s[j] = f2bf(bf2f(a[j]) + bf2f(l[j]));
    *reinterpret_cast<u16x8*>(Abw + row * 512 + (bc ^ ((row & 7) << 4))) = s;
  }
  __syncthreads();

  const char* Ab = (const char*)As;
  for (int cg = 0; cg < 2; ++cg) {
    const int c0w = cg * 128 + wave * 32;
    f32x4 acc[4][2];
#pragma unroll
    for (int i = 0; i < 4; ++i)
#pragma unroll
      for (int j = 0; j < 2; ++j) acc[i][j] = (f32x4){0.f, 0.f, 0.f, 0.f};

#pragma unroll
    for (int ks = 0; ks < 8; ++ks) {
      bf16x8 af[4];
#pragma unroll
      for (int mt = 0; mt < 4; ++mt) {
        const int rr = mt * 16 + lr;
        const int cb = (ks * 64 + g * 16) ^ ((rr & 7) << 4);
        af[mt] = *reinterpret_cast<const bf16x8*>(Ab + rr * 512 + cb);
      }
#pragma unroll
      for (int nt = 0; nt < 2; ++nt) {
        const bf16x8 b =
            *reinterpret_cast<const bf16x8*>(owT + (c0w + nt * 16 + lr) * 256 + ks * 32 + g * 8);
#pragma unroll
        for (int mt = 0; mt < 4; ++mt)
          acc[mt][nt] = __builtin_amdgcn_mfma_f32_16x16x32_bf16(b, af[mt], acc[mt][nt], 0, 0, 0);
      }
    }

#pragma unroll
    for (int mt = 0; mt < 4; ++mt) {
      const int tok = m0 + mt * 16 + lr;
#pragma unroll
      for (int nt = 0; nt < 2; ++nt) {
        const int col0 = c0w + nt * 16 + g * 4;
        const float4 ob4 = *reinterpret_cast<const float4*>(ob + col0);
        float4 o;
        o.x = acc[mt][nt][0] + ob4.x;
        o.y = acc[mt][nt][1] + ob4.y;
        o.z = acc[mt][nt][2] + ob4.z;
        o.w = acc[mt][nt][3] + ob4.w;
        *reinterpret_cast<float4*>(out + tok * 256 + col0) = o;
      }
    }
  }
}

// ---------------------------------------------------------------------------
extern "C" void kernel_launch(void* const* d_in, const int* in_sizes, int n_in,
                              void* d_out, int out_size, void* d_ws, size_t ws_size,
                              hipStream_t stream)
{
  const float* x      = (const float*)d_in[0];
  const float* sinp   = (const float*)d_in[1];
  const float* cosp   = (const float*)d_in[2];
  const float* mask_h = (const float*)d_in[3];
  const float* mask_w = (const float*)d_in[4];
  const float* q_w    = (const float*)d_in[5];
  const float* q_b    = (const float*)d_in[6];
  const float* k_w    = (const float*)d_in[7];
  const float* k_b    = (const float*)d_in[8];
  const float* v_w    = (const float*)d_in[9];
  const float* v_b    = (const float*)d_in[10];
  const float* lepe_w = (const float*)d_in[11];
  const float* lepe_b = (const float*)d_in[12];
  const float* out_w  = (const float*)d_in[13];
  const float* out_b  = (const float*)d_in[14];

  unsigned char* ws = (unsigned char*)d_ws;
  const size_t SZ = 33554432;  // 65536*256*2 bytes
  u16* qr    = (u16*)(ws);
  u16* kr    = (u16*)(ws + SZ);
  u16* vv    = (u16*)(ws + 2 * SZ);
  u16* v1    = (u16*)(ws + 3 * SZ);
  u16* lepe  = (u16*)(ws + 4 * SZ);
  u16* wqkvT = (u16*)(ws + 5 * SZ);
  u16* owT   = (u16*)(ws + 5 * SZ + 393216);
  float* bias   = (float*)(ws + 5 * SZ + 524288);
  float* maskTw = (float*)(ws + 5 * SZ + 528384);
  float* maskTh = (float*)(ws + 5 * SZ + 659456);
  u16* attn_out = vv;  // v is dead after conv + attnW

  pack_kernel<<<1280, 256, 0, stream>>>(q_w, q_b, k_w, k_b, v_w, v_b, out_w,
                                        mask_w, mask_h, wqkvT, bias, owT, maskTw, maskTh);
  qkv_gemm_kernel<<<512, 256, 0, stream>>>(x, wqkvT, bias, sinp, cosp, qr, kr, vv);
  lepe_kernel<<<2048, 256, 0, stream>>>(vv, lepe_w, lepe_b, lepe);
  attn_kernel<<<1024, 256, 0, stream>>>(qr, kr, vv, maskTw, v1, 0);
  attn_kernel<<<1024, 256, 0, stream>>>(qr, kr, v1, maskTh, attn_out, 1);
  out_gemm_kernel<<<1024, 256, 0, stream>>>(attn_out, lepe, owT, out_b, (float*)d_out);
}

// Round 15
// 276.007 us; speedup vs baseline: 1.2347x; 1.2347x over previous
//
#include <hip/hip_runtime.h>

typedef unsigned short u16;
typedef __attribute__((ext_vector_type(4))) float f32x4;
typedef __attribute__((ext_vector_type(8))) short bf16x8;
typedef __attribute__((ext_vector_type(8))) u16 u16x8;
typedef __attribute__((ext_vector_type(4))) u16 u16x4v;

#define DI __device__ __forceinline__

DI u16 f2bf(float f) {
  unsigned int x = __float_as_uint(f);
  unsigned int r = (x + 0x7fffu + ((x >> 16) & 1u)) >> 16;
  return (u16)r;
}
DI float bf2f(u16 u) { return __uint_as_float(((unsigned int)u) << 16); }

// ---------------------------------------------------------------------------
// K0: pack weights (R8 verbatim). wqkvT[768][256] bf16, bias[768] f32
// (k pre-scaled), owT[256][256] bf16.
// ---------------------------------------------------------------------------
__global__ __launch_bounds__(256) void pack_kernel(
    const float* __restrict__ qw, const float* __restrict__ qb,
    const float* __restrict__ kw, const float* __restrict__ kb,
    const float* __restrict__ vw, const float* __restrict__ vb,
    const float* __restrict__ ow,
    u16* __restrict__ wqkvT, float* __restrict__ bias, u16* __restrict__ owT)
{
  const int r = blockIdx.x;   // 0..1023
  const int t = threadIdx.x;  // 0..255
  if (r < 768) {
    const int p = r >> 8, c = r & 255;
    const float* wsrc = p == 0 ? qw : (p == 1 ? kw : vw);
    const float sc = (p == 1) ? 0.17677669529663687f : 1.0f;  // 1/sqrt(32)
    wqkvT[r * 256 + t] = f2bf(wsrc[t * 256 + c] * sc);
    if (t == 0) {
      const float* bs = p == 0 ? qb : (p == 1 ? kb : vb);
      bias[r] = bs[c] * sc;
    }
  } else {
    const int c = r - 768;
    owT[c * 256 + t] = f2bf(ow[t * 256 + c]);
  }
}

// ---------------------------------------------------------------------------
// K1a (R3 verbatim): x fp32 -> bf16, stored TILE-SWIZZLED so a linear
// global_load_lds copy of one 128x256 tile yields conflict-friendly
// ds_read_b128 A-fragment reads.
// ---------------------------------------------------------------------------
__global__ __launch_bounds__(256) void convert_kernel(
    const float* __restrict__ x, u16* __restrict__ xb)
{
  const int idx = blockIdx.x * 256 + threadIdx.x;  // 0..2097151
  const int tile = idx >> 12;        // 4096 chunks of 16B per 64KB tile
  const int within = idx & 4095;
  const int r = within >> 5;         // 32 chunks per 512B row
  const int bc = (within & 31) << 4;
  const int sbc = bc ^ ((r & 7) << 4);
  const int row = (tile << 7) + r;
  const float* sp = x + row * 256 + (sbc >> 1);
  const float4 a = *reinterpret_cast<const float4*>(sp);
  const float4 b = *reinterpret_cast<const float4*>(sp + 4);
  u16x8 o;
  o[0] = f2bf(a.x); o[1] = f2bf(a.y); o[2] = f2bf(a.z); o[3] = f2bf(a.w);
  o[4] = f2bf(b.x); o[5] = f2bf(b.y); o[6] = f2bf(b.z); o[7] = f2bf(b.w);
  *reinterpret_cast<u16x8*>(xb + (idx << 3)) = o;
}

// ---------------------------------------------------------------------------
// K1b (R3 verbatim — measured 74us): QKV + bias + RoPE. Grid 512: 128-row
// tiles, full 64KB A-tile staged ONCE via global_load_lds (async DMA from
// pre-swizzled xb — the 17us advantage over fused VALU staging), 6 column
// groups; epilogue transposes each wave's 16x64 slab through LDS so each
// lane owns 8 consecutive cols: RoPE in-lane, 16B full-line stores.
// ---------------------------------------------------------------------------
__global__ __launch_bounds__(256, 2) void qkv_gemm_kernel(
    const u16* __restrict__ xb, const u16* __restrict__ wT, const float* __restrict__ bias,
    const float* __restrict__ sinp, const float* __restrict__ cosp,
    u16* __restrict__ qr, u16* __restrict__ kr, u16* __restrict__ v)
{
  __shared__ u16 As[32768];        // 64 KB swizzled A-tile
  __shared__ float Tr[4][1024];    // 16 KB: per-wave 16x64 transpose slab
  const int t = threadIdx.x;
  const int wave = t >> 6, lane = t & 63;
  const int g = lane >> 4, lr = lane & 15;
  const int wr = wave >> 1, wc = wave & 1;
  const int m0 = blockIdx.x * 128;

  {
    const u16* src = xb + (size_t)blockIdx.x * 32768;
    auto gsrc = (const __attribute__((address_space(1))) u16*)src;
    auto lds = (__attribute__((address_space(3))) u16*)As;
#pragma unroll
    for (int i = 0; i < 16; ++i) {
      const int o = wave * 8192 + i * 512;  // u16 units; 1 KB per call
      __builtin_amdgcn_global_load_lds(
          (const __attribute__((address_space(1))) void*)(gsrc + o + lane * 8),
          (__attribute__((address_space(3))) void*)(lds + o), 16, 0, 0);
    }
  }
  __syncthreads();

  const char* Ab = (const char*)As;
  float* Trw = Tr[wave];
  const int tl = (lane >> 3);        // 0..7: token sub-row for epilogue reads
  const int cg8 = (lane & 7) * 8;    // 0..56: column chunk for epilogue reads

  for (int cg = 0; cg < 6; ++cg) {
    const int c0 = cg * 128;
    f32x4 acc[4][4];
#pragma unroll
    for (int i = 0; i < 4; ++i)
#pragma unroll
      for (int j = 0; j < 4; ++j) acc[i][j] = (f32x4){0.f, 0.f, 0.f, 0.f};

#pragma unroll
    for (int ks = 0; ks < 8; ++ks) {
      bf16x8 af[4], bfr[4];
#pragma unroll
      for (int mt = 0; mt < 4; ++mt) {
        const int rr = wr * 64 + mt * 16 + lr;
        const int cb = (ks * 64 + g * 16) ^ ((rr & 7) << 4);
        af[mt] = *reinterpret_cast<const bf16x8*>(Ab + rr * 512 + cb);
      }
#pragma unroll
      for (int nt = 0; nt < 4; ++nt)
        bfr[nt] = *reinterpret_cast<const bf16x8*>(wT + (c0 + wc * 64 + nt * 16 + lr) * 256 + ks * 32 + g * 8);
#pragma unroll
      for (int mt = 0; mt < 4; ++mt)
#pragma unroll
        for (int nt = 0; nt < 4; ++nt)
          acc[mt][nt] = __builtin_amdgcn_mfma_f32_16x16x32_bf16(af[mt], bfr[nt], acc[mt][nt], 0, 0, 0);
    }

    const int colb = c0 + wc * 64;
    const int proj = colb >> 8;  // 0=q 1=k 2=v (uniform per wave)
    u16* dst = proj == 0 ? qr : (proj == 1 ? kr : v);
    const int e0 = (colb & 255) + cg8;

    float bcv[4];
#pragma unroll
    for (int nt = 0; nt < 4; ++nt) bcv[nt] = bias[colb + nt * 16 + lr];

#pragma unroll
    for (int mt = 0; mt < 4; ++mt) {
      // scatter this wave's 16x64 slab into Tr: row = g*4+j, col = nt*16+lr,
      // col XOR (g<<4) keeps writes 2-way max (free).
#pragma unroll
      for (int nt = 0; nt < 4; ++nt)
#pragma unroll
        for (int j = 0; j < 4; ++j)
          Trw[(g * 4 + j) * 64 + ((nt * 16 + lr) ^ (g << 4))] = acc[mt][nt][j] + bcv[nt];
      asm volatile("s_waitcnt lgkmcnt(0)" ::: "memory");
#pragma unroll
      for (int r2 = 0; r2 < 2; ++r2) {
        const int row = tl + 8 * r2;                    // 0..15
        const int rb = row * 64 + (cg8 ^ ((row >> 2) << 4));
        const float4 v0 = *reinterpret_cast<const float4*>(Trw + rb);
        const float4 v1 = *reinterpret_cast<const float4*>(Trw + rb + 4);
        const int tok = m0 + wr * 64 + mt * 16 + row;
        float r0, r1, r2v, r3, r4, r5, r6, r7;
        if (proj < 2) {
          const int pos = tok & 4095;        // h*64 + w
          const int d0 = cg8 & 31;           // head-dim base (multiple of 8)
          const float* sp2 = sinp + pos * 32 + d0;
          const float* cp2 = cosp + pos * 32 + d0;
          const float4 s0 = *reinterpret_cast<const float4*>(sp2);
          const float4 s1 = *reinterpret_cast<const float4*>(sp2 + 4);
          const float4 cA = *reinterpret_cast<const float4*>(cp2);
          const float4 cB = *reinterpret_cast<const float4*>(cp2 + 4);
          r0  = v0.x * cA.x - v0.y * s0.x;
          r1  = v0.y * cA.y + v0.x * s0.y;
          r2v = v0.z * cA.z - v0.w * s0.z;
          r3  = v0.w * cA.w + v0.z * s0.w;
          r4  = v1.x * cB.x - v1.y * s1.x;
          r5  = v1.y * cB.y + v1.x * s1.y;
          r6  = v1.z * cB.z - v1.w * s1.z;
          r7  = v1.w * cB.w + v1.z * s1.w;
        } else {
          r0 = v0.x; r1 = v0.y; r2v = v0.z; r3 = v0.w;
          r4 = v1.x; r5 = v1.y; r6 = v1.z; r7 = v1.w;
        }
        u16x8 o;
        o[0] = f2bf(r0);  o[1] = f2bf(r1);  o[2] = f2bf(r2v); o[3] = f2bf(r3);
        o[4] = f2bf(r4);  o[5] = f2bf(r5);  o[6] = f2bf(r6);  o[7] = f2bf(r7);
        *reinterpret_cast<u16x8*>(dst + tok * 256 + e0) = o;
      }
      asm volatile("s_waitcnt lgkmcnt(0)" ::: "memory");  // drain before next mt overwrites Tr
    }
  }
}

// ---------------------------------------------------------------------------
// K2/K3 (R8 verbatim): axial attention. mode 0: over W (block=(b,h), stride
// 256). mode 1: over H (block=(b,w), stride 16384). V staged TRANSPOSED in
// LDS (Vt[d][tok], tok XOR-swizzled) so the PV B-fragment is one
// ds_read_b128. Pbuf wave-private -> no barriers inside the head loop.
// ---------------------------------------------------------------------------
__global__ __launch_bounds__(256, 2) void attn_kernel(
    const u16* __restrict__ qr, const u16* __restrict__ kr, const u16* __restrict__ vsrc,
    const float* __restrict__ mask, u16* __restrict__ dst, const int mode)
{
  __shared__ u16 Pbuf[4][64][72];  // 36 KB per-wave P
  __shared__ u16 Vt[256][80];      // 40 KB transposed V (row = d, col = swizzled tok)
  const int t = threadIdx.x;
  const int wave = t >> 6, lane = t & 63;
  const int g = lane >> 4, lr = lane & 15;
  const int b = blockIdx.x >> 6, o = blockIdx.x & 63;
  const int base = (mode == 0) ? (b * 4096 + o * 64) * 256 : (b * 4096 + o) * 256;
  const int ts = (mode == 0) ? 256 : 16384;

#pragma unroll
  for (int i = 0; i < 8; ++i) {
    const int c = t + 256 * i;          // 16B chunk, 0..2047
    const int tok = c >> 5, ch = c & 31;
    const u16x8 val = *reinterpret_cast<const u16x8*>(vsrc + base + tok * ts + ch * 8);
    const int tc = tok ^ ((ch & 7) * 8);
#pragma unroll
    for (int j = 0; j < 8; ++j) Vt[ch * 8 + j][tc] = val[j];
  }
  __syncthreads();

  for (int hh = 0; hh < 2; ++hh) {
    const int n = wave * 2 + hh;
    bf16x8 qf[4], kf[4];
#pragma unroll
    for (int mt = 0; mt < 4; ++mt) {
      qf[mt] = *reinterpret_cast<const bf16x8*>(qr + base + (mt * 16 + lr) * ts + n * 32 + g * 8);
      kf[mt] = *reinterpret_cast<const bf16x8*>(kr + base + (mt * 16 + lr) * ts + n * 32 + g * 8);
    }
    const f32x4 zero = (f32x4){0.f, 0.f, 0.f, 0.f};
    f32x4 s[4][4];
#pragma unroll
    for (int mt = 0; mt < 4; ++mt)
#pragma unroll
      for (int nt = 0; nt < 4; ++nt)
        s[mt][nt] = __builtin_amdgcn_mfma_f32_16x16x32_bf16(qf[mt], kf[nt], zero, 0, 0, 0);

    const float* mp = mask + n * 4096;
#pragma unroll
    for (int mt = 0; mt < 4; ++mt) {
#pragma unroll
      for (int j = 0; j < 4; ++j) {
        const int r = mt * 16 + g * 4 + j;
#pragma unroll
        for (int nt = 0; nt < 4; ++nt)
          s[mt][nt][j] += mp[r * 64 + nt * 16 + lr];
        float m = fmaxf(fmaxf(s[mt][0][j], s[mt][1][j]), fmaxf(s[mt][2][j], s[mt][3][j]));
        m = fmaxf(m, __shfl_xor(m, 1));
        m = fmaxf(m, __shfl_xor(m, 2));
        m = fmaxf(m, __shfl_xor(m, 4));
        m = fmaxf(m, __shfl_xor(m, 8));
        float sum = 0.f;
#pragma unroll
        for (int nt = 0; nt < 4; ++nt) {
          const float p = __expf(s[mt][nt][j] - m);
          s[mt][nt][j] = p;
          sum += p;
        }
        sum += __shfl_xor(sum, 1);
        sum += __shfl_xor(sum, 2);
        sum += __shfl_xor(sum, 4);
        sum += __shfl_xor(sum, 8);
        const float rs = 1.f / sum;
#pragma unroll
        for (int nt = 0; nt < 4; ++nt)
          Pbuf[wave][r][nt * 16 + lr] = f2bf(s[mt][nt][j] * rs);
      }
    }

    f32x4 oacc[4][2];
#pragma unroll
    for (int mt = 0; mt < 4; ++mt)
#pragma unroll
      for (int nd = 0; nd < 2; ++nd) oacc[mt][nd] = zero;

#pragma unroll
    for (int kt = 0; kt < 2; ++kt) {
      bf16x8 pa[4];
#pragma unroll
      for (int mt = 0; mt < 4; ++mt)
        pa[mt] = *reinterpret_cast<const bf16x8*>(&Pbuf[wave][mt * 16 + lr][kt * 32 + g * 8]);
#pragma unroll
      for (int nd = 0; nd < 2; ++nd) {
        const int dcol = n * 32 + nd * 16 + lr;
        const bf16x8 vb = *reinterpret_cast<const bf16x8*>(
            &Vt[dcol][(kt * 32 + g * 8) ^ (((dcol >> 3) & 7) * 8)]);
#pragma unroll
        for (int mt = 0; mt < 4; ++mt)
          oacc[mt][nd] = __builtin_amdgcn_mfma_f32_16x16x32_bf16(pa[mt], vb, oacc[mt][nd], 0, 0, 0);
      }
    }
#pragma unroll
    for (int mt = 0; mt < 4; ++mt)
#pragma unroll
      for (int nd = 0; nd < 2; ++nd)
#pragma unroll
        for (int j = 0; j < 4; ++j)
          dst[base + (mt * 16 + g * 4 + j) * ts + n * 32 + nd * 16 + lr] = f2bf(oacc[mt][nd][j]);
  }
}

// ---------------------------------------------------------------------------
// K4 (R4 verbatim): depthwise 5x5 conv (LePE). thread = 4 w-pixels x 8 ch.
// ---------------------------------------------------------------------------
__global__ __launch_bounds__(256) void lepe_kernel(
    const u16* __restrict__ v, const float* __restrict__ cw, const float* __restrict__ cb,
    u16* __restrict__ lepe)
{
  const int t = threadIdx.x;
  const int cg = t & 31, pg = t >> 5;     // 32 channel-groups x 8 pixel-groups
  const int c0 = cg * 8;
  const int rowi = blockIdx.x >> 1;       // b*64 + h, 0..1023
  const int w0 = (blockIdx.x & 1) * 32 + pg * 4;
  const int h = rowi & 63;

  float acc[4][8];
#pragma unroll
  for (int p = 0; p < 4; ++p)
#pragma unroll
    for (int j = 0; j < 8; ++j) acc[p][j] = 0.f;

#pragma unroll
  for (int dy = 0; dy < 5; ++dy) {
    const int hh = h + dy - 2;
    if ((unsigned)hh >= 64u) continue;
    const u16* vrow = v + (size_t)(rowi + dy - 2) * 64 * 256 + c0;
    float fin[8][8];
#pragma unroll
    for (int i = 0; i < 8; ++i) {
      const int ww = w0 - 2 + i;
      if ((unsigned)ww < 64u) {
        const u16x8 val = *reinterpret_cast<const u16x8*>(vrow + ww * 256);
#pragma unroll
        for (int j = 0; j < 8; ++j) fin[i][j] = bf2f(val[j]);
      } else {
#pragma unroll
        for (int j = 0; j < 8; ++j) fin[i][j] = 0.f;
      }
    }
#pragma unroll
    for (int dx = 0; dx < 5; ++dx) {
      const float* wp = cw + (dy * 5 + dx) * 256 + c0;
      const float4 wA = *reinterpret_cast<const float4*>(wp);
      const float4 wB = *reinterpret_cast<const float4*>(wp + 4);
      const float wv[8] = {wA.x, wA.y, wA.z, wA.w, wB.x, wB.y, wB.z, wB.w};
#pragma unroll
      for (int p = 0; p < 4; ++p)
#pragma unroll
        for (int j = 0; j < 8; ++j)
          acc[p][j] += fin[p + dx][j] * wv[j];
    }
  }

#pragma unroll
  for (int p = 0; p < 4; ++p) {
    u16x8 r;
#pragma unroll
    for (int j = 0; j < 8; ++j) r[j] = f2bf(acc[p][j] + cb[c0 + j]);
    *reinterpret_cast<u16x8*>(lepe + ((size_t)rowi * 64 + w0 + p) * 256 + c0) = r;
  }
}

// ---------------------------------------------------------------------------
// K5 (R8 verbatim): out = (attn_out + lepe) @ out_w + out_b, swapped-operand
// MFMA: lane owns (token=lr, 4 consecutive cols) -> float4 fp32 stores.
// ---------------------------------------------------------------------------
__global__ __launch_bounds__(256, 4) void out_gemm_kernel(
    const u16* __restrict__ ao, const u16* __restrict__ lep, const u16* __restrict__ owT,
    const float* __restrict__ ob, float* __restrict__ out)
{
  __shared__ u16 As[16384];  // 32 KB
  const int t = threadIdx.x;
  const int wave = t >> 6, lane = t & 63;
  const int g = lane >> 4, lr = lane & 15;
  const int m0 = blockIdx.x * 64;

  char* Abw = (char*)As;
#pragma unroll
  for (int i = 0; i < 8; ++i) {
    const int c = t + 256 * i;          // 16B chunk, 0..2047
    const int row = c >> 5, bc = (c & 31) << 4;
    const int off = (m0 + row) * 256 + (c & 31) * 8;
    const u16x8 a = *reinterpret_cast<const u16x8*>(ao + off);
    const u16x8 l = *reinterpret_cast<const u16x8*>(lep + off);
    u16x8 s;
#pragma unroll
    for (int j = 0; j < 8; ++j) s[j] = f2bf(bf2f(a[j]) + bf2f(l[j]));
    *reinterpret_cast<u16x8*>(Abw + row * 512 + (bc ^ ((row & 7) << 4))) = s;
  }
  __syncthreads();

  const char* Ab = (const char*)As;
  for (int cg = 0; cg < 2; ++cg) {
    const int c0w = cg * 128 + wave * 32;
    f32x4 acc[4][2];
#pragma unroll
    for (int i = 0; i < 4; ++i)
#pragma unroll
      for (int j = 0; j < 2; ++j) acc[i][j] = (f32x4){0.f, 0.f, 0.f, 0.f};

#pragma unroll
    for (int ks = 0; ks < 8; ++ks) {
      bf16x8 af[4], bfr[2];
#pragma unroll
      for (int mt = 0; mt < 4; ++mt) {
        const int rr = mt * 16 + lr;
        const int cb = (ks * 64 + g * 16) ^ ((rr & 7) << 4);
        af[mt] = *reinterpret_cast<const bf16x8*>(Ab + rr * 512 + cb);
      }
#pragma unroll
      for (int nt = 0; nt < 2; ++nt)
        bfr[nt] = *reinterpret_cast<const bf16x8*>(owT + (c0w + nt * 16 + lr) * 256 + ks * 32 + g * 8);
#pragma unroll
      for (int mt = 0; mt < 4; ++mt)
#pragma unroll
        for (int nt = 0; nt < 2; ++nt)
          acc[mt][nt] = __builtin_amdgcn_mfma_f32_16x16x32_bf16(bfr[nt], af[mt], acc[mt][nt], 0, 0, 0);
    }

#pragma unroll
    for (int mt = 0; mt < 4; ++mt) {
      const int tok = m0 + mt * 16 + lr;
#pragma unroll
      for (int nt = 0; nt < 2; ++nt) {
        const int col0 = c0w + nt * 16 + g * 4;
        const float4 ob4 = *reinterpret_cast<const float4*>(ob + col0);
        float4 o;
        o.x = acc[mt][nt][0] + ob4.x;
        o.y = acc[mt][nt][1] + ob4.y;
        o.z = acc[mt][nt][2] + ob4.z;
        o.w = acc[mt][nt][3] + ob4.w;
        *reinterpret_cast<float4*>(out + tok * 256 + col0) = o;
      }
    }
  }
}

// ---------------------------------------------------------------------------
extern "C" void kernel_launch(void* const* d_in, const int* in_sizes, int n_in,
                              void* d_out, int out_size, void* d_ws, size_t ws_size,
                              hipStream_t stream)
{
  const float* x      = (const float*)d_in[0];
  const float* sinp   = (const float*)d_in[1];
  const float* cosp   = (const float*)d_in[2];
  const float* mask_h = (const float*)d_in[3];
  const float* mask_w = (const float*)d_in[4];
  const float* q_w    = (const float*)d_in[5];
  const float* q_b    = (const float*)d_in[6];
  const float* k_w    = (const float*)d_in[7];
  const float* k_b    = (const float*)d_in[8];
  const float* v_w    = (const float*)d_in[9];
  const float* v_b    = (const float*)d_in[10];
  const float* lepe_w = (const float*)d_in[11];
  const float* lepe_b = (const float*)d_in[12];
  const float* out_w  = (const float*)d_in[13];
  const float* out_b  = (const float*)d_in[14];

  unsigned char* ws = (unsigned char*)d_ws;
  const size_t SZ = 33554432;  // 65536*256*2 bytes
  u16* qr    = (u16*)(ws);
  u16* kr    = (u16*)(ws + SZ);
  u16* vv    = (u16*)(ws + 2 * SZ);
  u16* v1    = (u16*)(ws + 3 * SZ);
  u16* xb    = (u16*)(ws + 4 * SZ);  // x as swizzled bf16; dead after qkv_gemm
  u16* lepe  = (u16*)(ws + 4 * SZ);  // reuses xb slot (written after qkv_gemm)
  u16* wqkvT = (u16*)(ws + 5 * SZ);
  u16* owT   = (u16*)(ws + 5 * SZ + 393216);
  float* bias = (float*)(ws + 5 * SZ + 393216 + 131072);
  u16* attn_out = vv;  // v is dead after conv + attnW

  pack_kernel<<<1024, 256, 0, stream>>>(q_w, q_b, k_w, k_b, v_w, v_b, out_w, wqkvT, bias, owT);
  convert_kernel<<<8192, 256, 0, stream>>>(x, xb);
  qkv_gemm_kernel<<<512, 256, 0, stream>>>(xb, wqkvT, bias, sinp, cosp, qr, kr, vv);
  lepe_kernel<<<2048, 256, 0, stream>>>(vv, lepe_w, lepe_b, lepe);
  attn_kernel<<<1024, 256, 0, stream>>>(qr, kr, vv, mask_w, v1, 0);
  attn_kernel<<<1024, 256, 0, stream>>>(qr, kr, v1, mask_h, attn_out, 1);
  out_gemm_kernel<<<1024, 256, 0, stream>>>(attn_out, lepe, owT, out_b, (float*)d_out);
}